// Round 4
// baseline (461.288 us; speedup 1.0000x reference)
//
#include <hip/hip_runtime.h>

// TriangleAttention, fused single-row-per-WG design for MI355X (gfx950).
// Row r = (b, s1): LN(z[r]) -> Q/K/V/bias proj (f16 MFMA) -> masked softmax
// over keys (+per-key bias) -> PV -> out-proj -> query-mask.
// 8 waves/WG: waves own 32 rows each for row-local phases; wave w = (head w>>1,
// query-half w&1) for attention.

#define SS 256
#define CC 128
#define NH 4
#define HD 32

typedef _Float16 f16;
typedef _Float16 f16x8 __attribute__((ext_vector_type(8)));
typedef _Float16 f16x4 __attribute__((ext_vector_type(4)));
typedef float f32x4 __attribute__((ext_vector_type(4)));

#define LOG2E 1.44269504088896340736f
// log2(e)/sqrt(D=32)
#define SCALE2 (1.44269504088896340736f * 0.17677669529663688110f)

// LDS byte map (total 151552 B = 148 KB, 1 WG/CU; gfx950 allows 160 KB)
#define REG_A 0        // zn [256][128] f16 (swz) -> later vT [128][256] f16 (swz)
#define REG_B 65536    // Qstage / kbuf / attnout [256][128] f16 (swz)
#define REG_P 131072   // per-wave P chunk [16 q][64 k] f16 (swz), 2048 B * 8 waves
#define REG_BIAS 147456// bias' [4][256] f32 (mask & log2e folded in)
#define SMEM_BYTES 151552

// natural [row][c] f16 with 16B-block XOR swizzle (row stride 256 B)
__device__ __forceinline__ int nat_addr(int row, int c) {
  return ((row << 8) + (c << 1)) ^ ((row & 7) << 4);
}
// vT [d][s] f16 (row stride 512 B)
__device__ __forceinline__ int vt_addr(int d, int s) {
  return ((d << 9) + (s << 1)) ^ ((d & 7) << 4);
}

__global__ void prep_weights(const float* __restrict__ wq, const float* __restrict__ wk,
                             const float* __restrict__ wv, const float* __restrict__ wo,
                             const float* __restrict__ wb, f16* __restrict__ ws) {
  int i = blockIdx.x * 256 + threadIdx.x;
  if (i < 16384)        ws[i] = (f16)wq[i];
  else if (i < 32768)   ws[i] = (f16)wk[i - 16384];
  else if (i < 49152)   ws[i] = (f16)wv[i - 32768];
  else if (i < 65536)   ws[i] = (f16)wo[i - 49152];
  else if (i < 67584) { // Wb padded [16][128], rows 4..15 zero
    int j = i - 65536, row = j >> 7, col = j & 127;
    ws[i] = (row < 4) ? (f16)wb[row * 128 + col] : (f16)0.f;
  }
}

__device__ __forceinline__ void proj_to_lds(char* smem, const f16x8 aZ[2][4],
                                            const f16* __restrict__ W,
                                            const float* __restrict__ bvec,
                                            int wid, int l15, int g, int dstBase) {
#pragma unroll
  for (int nt = 0; nt < 8; ++nt) {
    float bcol = bvec[nt * 16 + l15];
    f16x8 bfr[4];
#pragma unroll
    for (int kt = 0; kt < 4; ++kt)
      bfr[kt] = *reinterpret_cast<const f16x8*>(W + (nt * 16 + l15) * 128 + kt * 32 + g * 8);
#pragma unroll
    for (int mt = 0; mt < 2; ++mt) {
      f32x4 acc = {0.f, 0.f, 0.f, 0.f};
#pragma unroll
      for (int kt = 0; kt < 4; ++kt)
        acc = __builtin_amdgcn_mfma_f32_16x16x32_f16(aZ[mt][kt], bfr[kt], acc, 0, 0, 0);
#pragma unroll
      for (int p = 0; p < 4; ++p) {
        int row = wid * 32 + mt * 16 + g * 4 + p;
        *reinterpret_cast<f16*>(smem + dstBase + nat_addr(row, nt * 16 + l15)) =
            (f16)(acc[p] + bcol);
      }
    }
  }
}

__global__ __launch_bounds__(512, 2) void tri_fused(
    const float* __restrict__ z, const unsigned char* __restrict__ pm,
    const float* __restrict__ lnw, const float* __restrict__ lnb,
    const float* __restrict__ bq, const float* __restrict__ bk,
    const float* __restrict__ bv, const float* __restrict__ bo,
    const f16* __restrict__ wsbase, float* __restrict__ out) {
  __shared__ __align__(16) char smem[SMEM_BYTES];
  const f16* wq  = wsbase;
  const f16* wk  = wsbase + 16384;
  const f16* wv  = wsbase + 32768;
  const f16* wo  = wsbase + 49152;
  const f16* wbp = wsbase + 65536;

  const int r = blockIdx.x;
  const int tid = threadIdx.x;
  const int wid = tid >> 6;
  const int lane = tid & 63;
  const int g = lane >> 4, l15 = lane & 15;

  // ---- mask dtype sniff: bool(1B) vs int32(4B) vs float32(4B) -------------
  // Inspect the first 256 words (valid under every interpretation).
  //  - int32 {0,1}: every word <= 1.
  //  - float32 {0.0f,1.0f}: every word in {0, 0x3F800000}, at least one 1.0f.
  //  - bool/u8: random {0,1} bytes make words like 0x00010001 (>1) with
  //    overwhelming probability (misclassify P ~ 2^-768).
  // Both 4-byte variants reduce to "word != 0"; result is wave-uniform.
  const unsigned int* pm32 = reinterpret_cast<const unsigned int*>(pm);
  int notI32 = 0, notF32 = 0, f32seen = 0;
  for (int i = lane; i < 256; i += 64) {
    unsigned int w = pm32[i];
    if (w > 1u) notI32 = 1;
    if (w != 0u && w != 0x3F800000u) notF32 = 1;
    if (w == 0x3F800000u) f32seen = 1;
  }
  const bool isI32 = (__ballot(notI32) == 0ULL);
  const bool isF32 = !isI32 && (__ballot(notF32) == 0ULL) && (__ballot(f32seen) != 0ULL);
  const bool mask4B = isI32 || isF32;

  // ---------------- P1: LayerNorm (rows wid*32..+32, 2 rows per iter) -------
  {
    const int c4 = (lane & 31) * 4;
    const int half = lane >> 5;
    float4 w4 = *reinterpret_cast<const float4*>(lnw + c4);
    float4 b4 = *reinterpret_cast<const float4*>(lnb + c4);
#pragma unroll 4
    for (int i = 0; i < 16; ++i) {
      int row = wid * 32 + i * 2 + half;
      float4 v = *reinterpret_cast<const float4*>(z + ((size_t)r * SS + row) * CC + c4);
      float s1 = v.x + v.y + v.z + v.w;
      float s2 = v.x * v.x + v.y * v.y + v.z * v.z + v.w * v.w;
#pragma unroll
      for (int m = 1; m <= 16; m <<= 1) { s1 += __shfl_xor(s1, m); s2 += __shfl_xor(s2, m); }
      float mu = s1 * (1.0f / 128.0f);
      float var = s2 * (1.0f / 128.0f) - mu * mu;
      float rs = rsqrtf(var + 1e-5f);
      f16x4 h;
      h[0] = (f16)((v.x - mu) * rs * w4.x + b4.x);
      h[1] = (f16)((v.y - mu) * rs * w4.y + b4.y);
      h[2] = (f16)((v.z - mu) * rs * w4.z + b4.z);
      h[3] = (f16)((v.w - mu) * rs * w4.w + b4.w);
      *reinterpret_cast<f16x4*>(smem + REG_A + nat_addr(row, c4)) = h;
    }
  }
  // zn A-fragments for this wave's 32 rows (same-wave data; LDS in-order)
  f16x8 aZ[2][4];
#pragma unroll
  for (int mt = 0; mt < 2; ++mt)
#pragma unroll
    for (int kt = 0; kt < 4; ++kt)
      aZ[mt][kt] = *reinterpret_cast<const f16x8*>(
          smem + REG_A + nat_addr(wid * 32 + mt * 16 + l15, kt * 32 + g * 8));

  // ---------------- P2a: Q projection -> region B --------------------------
  proj_to_lds(smem, aZ, wq, bq, wid, l15, g, REG_B);
  __syncthreads();  // Q staged

  // P2b: load this wave's Q A-fragments (head h, query half qh)
  const int h = wid >> 1, qh = wid & 1;
  f16x8 qreg[8];
#pragma unroll
  for (int qb = 0; qb < 8; ++qb)
    qreg[qb] = *reinterpret_cast<const f16x8*>(
        smem + REG_B + nat_addr(qh * 128 + qb * 16 + l15, h * 32 + g * 8));
  __syncthreads();  // all q-reads done before K overwrites region B

  // ---------------- P2c: K projection -> region B, bias', V (regs) ---------
  proj_to_lds(smem, aZ, wk, bk, wid, l15, g, REG_B);

  float mask8[8];
#pragma unroll
  for (int mt = 0; mt < 2; ++mt)
#pragma unroll
    for (int p = 0; p < 4; ++p) {
      size_t e = (size_t)r * SS + wid * 32 + mt * 16 + g * 4 + p;
      bool mv = mask4B ? (pm32[e] != 0u) : (pm[e] != 0);
      mask8[mt * 4 + p] = mv ? 1.0f : 0.0f;
    }

  {  // bias' = mask ? (zn . Wb) * log2e : -60000   (keys = this wave's rows)
    f16x8 bfr[4];
#pragma unroll
    for (int kt = 0; kt < 4; ++kt)
      bfr[kt] = *reinterpret_cast<const f16x8*>(wbp + l15 * 128 + kt * 32 + g * 8);
#pragma unroll
    for (int mt = 0; mt < 2; ++mt) {
      f32x4 acc = {0.f, 0.f, 0.f, 0.f};
#pragma unroll
      for (int kt = 0; kt < 4; ++kt)
        acc = __builtin_amdgcn_mfma_f32_16x16x32_f16(aZ[mt][kt], bfr[kt], acc, 0, 0, 0);
      if (l15 < 4) {
#pragma unroll
        for (int p = 0; p < 4; ++p) {
          int key = wid * 32 + mt * 16 + g * 4 + p;
          float bb = (mask8[mt * 4 + p] != 0.f) ? acc[p] * LOG2E : -60000.0f;
          *reinterpret_cast<float*>(smem + REG_BIAS + l15 * 1024 + key * 4) = bb;
        }
      }
    }
  }

  f16x4 vreg[2][8];  // V rows (this wave's 32 rows), f16, 4 consecutive s per frag
#pragma unroll
  for (int nt = 0; nt < 8; ++nt) {
    float bcol = bv[nt * 16 + l15];
    f16x8 bfr[4];
#pragma unroll
    for (int kt = 0; kt < 4; ++kt)
      bfr[kt] = *reinterpret_cast<const f16x8*>(wv + (nt * 16 + l15) * 128 + kt * 32 + g * 8);
#pragma unroll
    for (int mt = 0; mt < 2; ++mt) {
      f32x4 acc = {0.f, 0.f, 0.f, 0.f};
#pragma unroll
      for (int kt = 0; kt < 4; ++kt)
        acc = __builtin_amdgcn_mfma_f32_16x16x32_f16(aZ[mt][kt], bfr[kt], acc, 0, 0, 0);
      f16x4 pk;
#pragma unroll
      for (int p = 0; p < 4; ++p) pk[p] = (f16)(acc[p] + bcol);
      vreg[mt][nt] = pk;
    }
  }
  __syncthreads();  // all zn reads + kbuf/bias writes complete

  // vT scatter over region A (V transposed [d][s]); b64 = 4 consecutive s
#pragma unroll
  for (int mt = 0; mt < 2; ++mt)
#pragma unroll
    for (int nt = 0; nt < 8; ++nt) {
      int d = nt * 16 + l15;
      int s0 = wid * 32 + mt * 16 + g * 4;
      *reinterpret_cast<f16x4*>(smem + REG_A + vt_addr(d, s0)) = vreg[mt][nt];
    }
  __syncthreads();  // kbuf + vT + bias' ready

  // ---------------- P3: attention (no barriers; wave-private) ---------------
  float biasreg[16];
#pragma unroll
  for (int nt = 0; nt < 16; ++nt)
    biasreg[nt] = *reinterpret_cast<const float*>(
        smem + REG_BIAS + h * 1024 + (nt * 16 + l15) * 4);

  const int pbase = REG_P + wid * 2048;
  f16x4 attn16[8][2];

  for (int qb = 0; qb < 8; ++qb) {
    // S = Q . K^T  (C-frag: row=query 4g+p, col=key l15+16nt)
    f32x4 sv[16];
#pragma unroll
    for (int nt = 0; nt < 16; ++nt) {
      f16x8 kf = *reinterpret_cast<const f16x8*>(
          smem + REG_B + nat_addr(nt * 16 + l15, h * 32 + g * 8));
      f32x4 zero = {0.f, 0.f, 0.f, 0.f};
      sv[nt] = __builtin_amdgcn_mfma_f32_16x16x32_f16(qreg[qb], kf, zero, 0, 0, 0);
    }
    // softmax (no max-sub: logits tiny; masked bias' = -60000 -> exp2 -> 0)
    float Lp[4] = {0.f, 0.f, 0.f, 0.f};
#pragma unroll
    for (int nt = 0; nt < 16; ++nt)
#pragma unroll
      for (int p = 0; p < 4; ++p) {
        float x = fmaf(sv[nt][p], SCALE2, biasreg[nt]);
        float e = __builtin_amdgcn_exp2f(x);
        sv[nt][p] = e;
        Lp[p] += e;
      }
#pragma unroll
    for (int m = 1; m <= 8; m <<= 1)
#pragma unroll
      for (int p = 0; p < 4; ++p) Lp[p] += __shfl_xor(Lp[p], m);

    // PV via per-wave LDS repack in 64-key chunks
    f32x4 oacc[2] = {{0.f, 0.f, 0.f, 0.f}, {0.f, 0.f, 0.f, 0.f}};
#pragma unroll
    for (int kc = 0; kc < 4; ++kc) {
#pragma unroll
      for (int nt2 = 0; nt2 < 4; ++nt2) {
        int nt = kc * 4 + nt2;
#pragma unroll
        for (int p = 0; p < 4; ++p) {
          int q = g * 4 + p, kk = nt2 * 16 + l15;
          int byte = pbase + (((q << 7) + (kk << 1)) ^ ((q & 7) << 4));
          *reinterpret_cast<f16*>(smem + byte) = (f16)sv[nt][p];
        }
      }
#pragma unroll
      for (int kt2 = 0; kt2 < 2; ++kt2) {
        int abyte = pbase + (((l15 << 7) + kt2 * 64 + g * 16) ^ ((l15 & 7) << 4));
        f16x8 pf = *reinterpret_cast<const f16x8*>(smem + abyte);
#pragma unroll
        for (int dnt = 0; dnt < 2; ++dnt) {
          int d = h * 32 + dnt * 16 + l15;
          f16x8 vf = *reinterpret_cast<const f16x8*>(
              smem + REG_A + vt_addr(d, kc * 64 + kt2 * 32 + g * 8));
          oacc[dnt] = __builtin_amdgcn_mfma_f32_16x16x32_f16(pf, vf, oacc[dnt], 0, 0, 0);
        }
      }
    }
    float lr[4];
#pragma unroll
    for (int p = 0; p < 4; ++p) lr[p] = 1.0f / fmaxf(Lp[p], 1e-20f);
#pragma unroll
    for (int dnt = 0; dnt < 2; ++dnt) {
      f16x4 pk;
#pragma unroll
      for (int p = 0; p < 4; ++p) pk[p] = (f16)(oacc[dnt][p] * lr[p]);
      attn16[qb][dnt] = pk;
    }
  }
  __syncthreads();  // everyone done reading kbuf

  // attnout scatter into region B (natural layout)
#pragma unroll
  for (int qb = 0; qb < 8; ++qb)
#pragma unroll
    for (int dnt = 0; dnt < 2; ++dnt)
#pragma unroll
      for (int p = 0; p < 4; ++p) {
        int row = qh * 128 + qb * 16 + g * 4 + p;
        int col = h * 32 + dnt * 16 + l15;
        *reinterpret_cast<f16*>(smem + REG_B + nat_addr(row, col)) = attn16[qb][dnt][p];
      }
  __syncthreads();

  // ---------------- P4: output projection + query mask ----------------------
  f16x8 aO[2][4];
#pragma unroll
  for (int mt = 0; mt < 2; ++mt)
#pragma unroll
    for (int kt = 0; kt < 4; ++kt)
      aO[mt][kt] = *reinterpret_cast<const f16x8*>(
          smem + REG_B + nat_addr(wid * 32 + mt * 16 + l15, kt * 32 + g * 8));
#pragma unroll
  for (int nt = 0; nt < 8; ++nt) {
    float bcol = bo[nt * 16 + l15];
    f16x8 bfr[4];
#pragma unroll
    for (int kt = 0; kt < 4; ++kt)
      bfr[kt] = *reinterpret_cast<const f16x8*>(wo + (nt * 16 + l15) * 128 + kt * 32 + g * 8);
#pragma unroll
    for (int mt = 0; mt < 2; ++mt) {
      f32x4 acc = {0.f, 0.f, 0.f, 0.f};
#pragma unroll
      for (int kt = 0; kt < 4; ++kt)
        acc = __builtin_amdgcn_mfma_f32_16x16x32_f16(aO[mt][kt], bfr[kt], acc, 0, 0, 0);
#pragma unroll
      for (int p = 0; p < 4; ++p) {
        int row = wid * 32 + mt * 16 + g * 4 + p;
        out[((size_t)r * SS + row) * CC + nt * 16 + l15] =
            (acc[p] + bcol) * mask8[mt * 4 + p];
      }
    }
  }
}

extern "C" void kernel_launch(void* const* d_in, const int* in_sizes, int n_in,
                              void* d_out, int out_size, void* d_ws, size_t ws_size,
                              hipStream_t stream) {
  const float* z   = (const float*)d_in[0];
  const unsigned char* pmask = (const unsigned char*)d_in[1];  // dtype sniffed on device
  const float* lnw = (const float*)d_in[2];
  const float* lnb = (const float*)d_in[3];
  const float* Wq  = (const float*)d_in[4];
  const float* bq  = (const float*)d_in[5];
  const float* Wk  = (const float*)d_in[6];
  const float* bk  = (const float*)d_in[7];
  const float* Wv  = (const float*)d_in[8];
  const float* bv  = (const float*)d_in[9];
  const float* Wb  = (const float*)d_in[10];
  const float* Wo  = (const float*)d_in[11];
  const float* bo  = (const float*)d_in[12];
  f16* ws = (f16*)d_ws;

  prep_weights<<<264, 256, 0, stream>>>(Wq, Wk, Wv, Wo, Wb, ws);
  tri_fused<<<512, 512, 0, stream>>>(z, pmask, lnw, lnb, bq, bk, bv, bo,
                                     ws, (float*)d_out);
}

// Round 8
// 283.819 us; speedup vs baseline: 1.6253x; 1.6253x over previous
//
#include <hip/hip_runtime.h>

// TriangleAttention fused, per-head-phased design for MI355X (gfx950).
// WG = one row r (512 thr, 8 waves); wave w owns rows [32w,32w+32) as
// queries for ALL heads. Per head h: stage K/V/bias for all 256 keys in
// small LDS (16+16+4 KB), each wave attends its 32 queries. LDS 76 KB ->
// 2 WG/CU (grid 512 = fully resident); streaming softmax keeps VGPR <= 128.
// r5->r6: pb_addr swizzle was non-bijective (bit-6 escape overflowed the
// 1KB P-slice into BS -> inf/NaN). PB now 4 slots x 2KB, 128B rows,
// (q&7)<<4 swizzle (bits 4-6 < 128 = legal), wave parity picks key-half.

#define SS 256
#define CC 128

typedef _Float16 f16;
typedef _Float16 f16x8 __attribute__((ext_vector_type(8)));
typedef _Float16 f16x4 __attribute__((ext_vector_type(4)));
typedef float f32x4 __attribute__((ext_vector_type(4)));

#define LOG2E 1.44269504088896340736f
#define SCALE2 (1.44269504088896340736f * 0.17677669529663688110f)  // log2e/sqrt(32)

// LDS map: 77824 B/WG -> 2 WG/CU (155648 <= 163840)
#define ZS_BASE 0       // 8 x 4KB per-wave scratch (LN chunks / Q-stage / O-stage)
#define KB_BASE 32768   // per-head K  [256 key][32 d] f16, swz
#define VT_BASE 49152   // per-head V^T [32 d][256 key] f16, swz
#define PB_BASE 65536   // 4 x 2KB wave-pair P repack [16 q][64 kk] f16, swz
#define BS_BASE 73728   // bias' [4][256] f32 (mask & log2e folded)
#define SMEM_BYTES 77824

// [16 rows][128 c] f16, row stride 256B (LN / O staging); XOR bits 4-6 < 256 OK
__device__ __forceinline__ int zs_addr(int base, int row, int c) {
  return base + (row << 8) + (((c << 1)) ^ ((row & 7) << 4));
}
// [32 q][32 d] f16, row stride 64B (Q staging); XOR bits 4-5 < 64 OK
__device__ __forceinline__ int q_addr(int base, int q, int d) {
  return base + (q << 6) + ((d << 1) ^ ((q & 3) << 4));
}
// K [256 key][32 d] f16, row stride 64B; XOR bits 4-5 < 64 OK
__device__ __forceinline__ int k_addr(int key, int d) {
  return KB_BASE + (key << 6) + ((d << 1) ^ ((key & 3) << 4));
}
// V^T [32 d][256 key] f16, row stride 512B; XOR bits 4-6 < 512 OK
__device__ __forceinline__ int vt_addr(int d, int key) {
  return VT_BASE + (d << 9) + ((key << 1) ^ ((d & 7) << 4));
}
// P [16 q][64 kk] f16, row stride 128B; XOR bits 4-6 < 128 -> bijective
__device__ __forceinline__ int pb_addr(int base, int q, int kk) {
  return base + (q << 7) + ((kk << 1) ^ ((q & 7) << 4));
}

__global__ void prep_weights(const float* __restrict__ wq, const float* __restrict__ wk,
                             const float* __restrict__ wv, const float* __restrict__ wo,
                             const float* __restrict__ wb, f16* __restrict__ ws) {
  int i = blockIdx.x * 256 + threadIdx.x;
  if (i < 16384)        ws[i] = (f16)wq[i];
  else if (i < 32768)   ws[i] = (f16)wk[i - 16384];
  else if (i < 49152)   ws[i] = (f16)wv[i - 32768];
  else if (i < 65536)   ws[i] = (f16)wo[i - 49152];
  else if (i < 67584) { // Wb padded [16][128], rows 4..15 zero
    int j = i - 65536, row = j >> 7, col = j & 127;
    ws[i] = (row < 4) ? (f16)wb[row * 128 + col] : (f16)0.f;
  }
}

__global__ __launch_bounds__(512, 4) void tri_fused(
    const float* __restrict__ z, const unsigned char* __restrict__ pm,
    const float* __restrict__ lnw, const float* __restrict__ lnb,
    const float* __restrict__ bq, const float* __restrict__ bk,
    const float* __restrict__ bv, const float* __restrict__ bo,
    const f16* __restrict__ wsbase, float* __restrict__ out) {
  __shared__ __align__(16) char smem[SMEM_BYTES];
  const f16* wq  = wsbase;
  const f16* wk  = wsbase + 16384;
  const f16* wv  = wsbase + 32768;
  const f16* wo  = wsbase + 49152;
  const f16* wbp = wsbase + 65536;

  const int r = blockIdx.x;
  const int tid = threadIdx.x;
  const int wid = tid >> 6;
  const int lane = tid & 63;
  const int g = lane >> 4, l15 = lane & 15;
  const int ZS0 = ZS_BASE + wid * 4096;
  const int PB0 = PB_BASE + (wid >> 1) * 2048;  // wave-pair slot
  const int KOFF = (wid & 1) * 32;              // key-half within slot

  // ---- mask dtype sniff (verified r4): bool(1B)/int32/float32 -------------
  const unsigned int* pm32 = reinterpret_cast<const unsigned int*>(pm);
  int notI32 = 0, notF32 = 0, f32seen = 0;
  for (int i = lane; i < 256; i += 64) {
    unsigned int w = pm32[i];
    if (w > 1u) notI32 = 1;
    if (w != 0u && w != 0x3F800000u) notF32 = 1;
    if (w == 0x3F800000u) f32seen = 1;
  }
  const bool isI32 = (__ballot(notI32) == 0ULL);
  const bool isF32 = !isI32 && (__ballot(notF32) == 0ULL) && (__ballot(f32seen) != 0ULL);
  const bool mask4B = isI32 || isF32;

  // ---------------- P1: LayerNorm in 2 chunks of 16 rows -> aZ frags -------
  f16x8 aZ[2][4];
  {
    const int c4 = (lane & 31) * 4;
    const int half = lane >> 5;
    float4 w4 = *reinterpret_cast<const float4*>(lnw + c4);
    float4 b4 = *reinterpret_cast<const float4*>(lnb + c4);
#pragma unroll
    for (int mt = 0; mt < 2; ++mt) {
#pragma unroll 2
      for (int i = 0; i < 8; ++i) {
        int rloc = i * 2 + half;
        int row = wid * 32 + mt * 16 + rloc;
        float4 v = *reinterpret_cast<const float4*>(z + ((size_t)r * SS + row) * CC + c4);
        float s1 = v.x + v.y + v.z + v.w;
        float s2 = v.x * v.x + v.y * v.y + v.z * v.z + v.w * v.w;
#pragma unroll
        for (int m = 1; m <= 16; m <<= 1) { s1 += __shfl_xor(s1, m); s2 += __shfl_xor(s2, m); }
        float mu = s1 * (1.0f / 128.0f);
        float var = s2 * (1.0f / 128.0f) - mu * mu;
        float rs = rsqrtf(var + 1e-5f);
        f16x4 hv;
        hv[0] = (f16)((v.x - mu) * rs * w4.x + b4.x);
        hv[1] = (f16)((v.y - mu) * rs * w4.y + b4.y);
        hv[2] = (f16)((v.z - mu) * rs * w4.z + b4.z);
        hv[3] = (f16)((v.w - mu) * rs * w4.w + b4.w);
        *reinterpret_cast<f16x4*>(smem + zs_addr(ZS0, rloc, c4)) = hv;
      }
      // wave-local write->read; compiler orders via lgkmcnt
#pragma unroll
      for (int kt = 0; kt < 4; ++kt)
        aZ[mt][kt] = *reinterpret_cast<const f16x8*>(
            smem + zs_addr(ZS0, l15, kt * 32 + g * 8));
    }
  }

  // ---------------- P2: bias' all 4 heads (keys = own rows) ----------------
  {
    f16x8 bfr[4];
#pragma unroll
    for (int kt = 0; kt < 4; ++kt)
      bfr[kt] = *reinterpret_cast<const f16x8*>(wbp + l15 * 128 + kt * 32 + g * 8);
#pragma unroll
    for (int mt = 0; mt < 2; ++mt) {
      f32x4 acc = {0.f, 0.f, 0.f, 0.f};
#pragma unroll
      for (int kt = 0; kt < 4; ++kt)
        acc = __builtin_amdgcn_mfma_f32_16x16x32_f16(aZ[mt][kt], bfr[kt], acc, 0, 0, 0);
      if (l15 < 4) {
#pragma unroll
        for (int p = 0; p < 4; ++p) {
          int key = wid * 32 + mt * 16 + g * 4 + p;
          size_t e = (size_t)r * SS + key;
          bool mv = mask4B ? (pm32[e] != 0u) : (pm[e] != 0);
          float bb = mv ? acc[p] * LOG2E : -60000.0f;
          *reinterpret_cast<float*>(smem + BS_BASE + l15 * 1024 + key * 4) = bb;
        }
      }
    }
  }

  // ---------------- Head loop --------------------------------------------
  f16x4 att[4][2][2];  // [h][mt][dnt], static-indexed (all loops unrolled)
#pragma unroll
  for (int h = 0; h < 4; ++h) {
    // Q-proj -> own ZS slice [32 q][32 d], then qreg A-frags (wave-local)
#pragma unroll
    for (int nt = 0; nt < 2; ++nt) {
      int dg = h * 32 + nt * 16 + l15;
      float bcol = bq[dg];
      f16x8 bfr[4];
#pragma unroll
      for (int kt = 0; kt < 4; ++kt)
        bfr[kt] = *reinterpret_cast<const f16x8*>(wq + dg * 128 + kt * 32 + g * 8);
#pragma unroll
      for (int mt = 0; mt < 2; ++mt) {
        f32x4 acc = {0.f, 0.f, 0.f, 0.f};
#pragma unroll
        for (int kt = 0; kt < 4; ++kt)
          acc = __builtin_amdgcn_mfma_f32_16x16x32_f16(aZ[mt][kt], bfr[kt], acc, 0, 0, 0);
#pragma unroll
        for (int p = 0; p < 4; ++p)
          *reinterpret_cast<f16*>(smem + q_addr(ZS0, mt * 16 + g * 4 + p, nt * 16 + l15)) =
              (f16)(acc[p] + bcol);
      }
    }
    f16x8 qreg[2];
#pragma unroll
    for (int mt = 0; mt < 2; ++mt)
      qreg[mt] = *reinterpret_cast<const f16x8*>(
          smem + q_addr(ZS0, mt * 16 + l15, g * 8));

    __syncthreads();  // all waves done reading prev head's KB/VT

    // K-proj -> KB, V-proj -> VT (keys = own rows)
#pragma unroll
    for (int nt = 0; nt < 2; ++nt) {
      int dg = h * 32 + nt * 16 + l15;
      float bcK = bk[dg], bcV = bv[dg];
      f16x8 bK[4], bV[4];
#pragma unroll
      for (int kt = 0; kt < 4; ++kt) {
        bK[kt] = *reinterpret_cast<const f16x8*>(wk + dg * 128 + kt * 32 + g * 8);
        bV[kt] = *reinterpret_cast<const f16x8*>(wv + dg * 128 + kt * 32 + g * 8);
      }
#pragma unroll
      for (int mt = 0; mt < 2; ++mt) {
        f32x4 aK = {0.f, 0.f, 0.f, 0.f}, aV = {0.f, 0.f, 0.f, 0.f};
#pragma unroll
        for (int kt = 0; kt < 4; ++kt) {
          aK = __builtin_amdgcn_mfma_f32_16x16x32_f16(aZ[mt][kt], bK[kt], aK, 0, 0, 0);
          aV = __builtin_amdgcn_mfma_f32_16x16x32_f16(aZ[mt][kt], bV[kt], aV, 0, 0, 0);
        }
        int key0 = wid * 32 + mt * 16 + g * 4;
#pragma unroll
        for (int p = 0; p < 4; ++p)
          *reinterpret_cast<f16*>(smem + k_addr(key0 + p, nt * 16 + l15)) = (f16)(aK[p] + bcK);
        f16x4 pk;
#pragma unroll
        for (int p = 0; p < 4; ++p) pk[p] = (f16)(aV[p] + bcV);
        *reinterpret_cast<f16x4*>(smem + vt_addr(nt * 16 + l15, key0)) = pk;
      }
    }
    __syncthreads();  // KB/VT (and BS for h=0) visible

    // attention: 32 own queries vs 256 keys, streamed per 32-key chunk
#pragma unroll
    for (int mt = 0; mt < 2; ++mt) {
      f32x4 oacc0 = {0.f, 0.f, 0.f, 0.f}, oacc1 = {0.f, 0.f, 0.f, 0.f};
      float Lp[4] = {0.f, 0.f, 0.f, 0.f};
      for (int kc = 0; kc < 8; ++kc) {
        f16x8 kf0 = *reinterpret_cast<const f16x8*>(smem + k_addr(kc * 32 + l15, g * 8));
        f16x8 kf1 = *reinterpret_cast<const f16x8*>(smem + k_addr(kc * 32 + 16 + l15, g * 8));
        f32x4 zero = {0.f, 0.f, 0.f, 0.f};
        f32x4 s0 = __builtin_amdgcn_mfma_f32_16x16x32_f16(qreg[mt], kf0, zero, 0, 0, 0);
        f32x4 s1 = __builtin_amdgcn_mfma_f32_16x16x32_f16(qreg[mt], kf1, zero, 0, 0, 0);
        float b0 = *reinterpret_cast<const float*>(
            smem + BS_BASE + h * 1024 + (kc * 32 + l15) * 4);
        float b1 = *reinterpret_cast<const float*>(
            smem + BS_BASE + h * 1024 + (kc * 32 + 16 + l15) * 4);
#pragma unroll
        for (int p = 0; p < 4; ++p) {
          float e0 = __builtin_amdgcn_exp2f(fmaf(s0[p], SCALE2, b0));
          float e1 = __builtin_amdgcn_exp2f(fmaf(s1[p], SCALE2, b1));
          Lp[p] += e0 + e1;
          *reinterpret_cast<f16*>(smem + pb_addr(PB0, g * 4 + p, KOFF + l15)) = (f16)e0;
          *reinterpret_cast<f16*>(smem + pb_addr(PB0, g * 4 + p, KOFF + 16 + l15)) = (f16)e1;
        }
        f16x8 pf = *reinterpret_cast<const f16x8*>(smem + pb_addr(PB0, l15, KOFF + g * 8));
        f16x8 vf0 = *reinterpret_cast<const f16x8*>(smem + vt_addr(l15, kc * 32 + g * 8));
        f16x8 vf1 = *reinterpret_cast<const f16x8*>(smem + vt_addr(16 + l15, kc * 32 + g * 8));
        oacc0 = __builtin_amdgcn_mfma_f32_16x16x32_f16(pf, vf0, oacc0, 0, 0, 0);
        oacc1 = __builtin_amdgcn_mfma_f32_16x16x32_f16(pf, vf1, oacc1, 0, 0, 0);
      }
#pragma unroll
      for (int m = 1; m <= 8; m <<= 1)
#pragma unroll
        for (int p = 0; p < 4; ++p) Lp[p] += __shfl_xor(Lp[p], m);
#pragma unroll
      for (int p = 0; p < 4; ++p) {
        float lr = 1.0f / fmaxf(Lp[p], 1e-20f);
        att[h][mt][0][p] = (f16)(oacc0[p] * lr);
        att[h][mt][1][p] = (f16)(oacc1[p] * lr);
      }
    }
  }

  // ---------------- O-proj + query mask (wave-local staging) ---------------
#pragma unroll
  for (int mt = 0; mt < 2; ++mt) {
#pragma unroll
    for (int h = 0; h < 4; ++h)
#pragma unroll
      for (int dnt = 0; dnt < 2; ++dnt)
#pragma unroll
        for (int p = 0; p < 4; ++p)
          *reinterpret_cast<f16*>(
              smem + zs_addr(ZS0, g * 4 + p, h * 32 + dnt * 16 + l15)) = att[h][mt][dnt][p];
    f16x8 aO[4];
#pragma unroll
    for (int kt = 0; kt < 4; ++kt)
      aO[kt] = *reinterpret_cast<const f16x8*>(smem + zs_addr(ZS0, l15, kt * 32 + g * 8));
    float qm[4];
#pragma unroll
    for (int p = 0; p < 4; ++p) {
      size_t e = (size_t)r * SS + wid * 32 + mt * 16 + g * 4 + p;
      qm[p] = (mask4B ? (pm32[e] != 0u) : (pm[e] != 0)) ? 1.0f : 0.0f;
    }
#pragma unroll
    for (int nt = 0; nt < 8; ++nt) {
      float bcol = bo[nt * 16 + l15];
      f16x8 bfr[4];
#pragma unroll
      for (int kt = 0; kt < 4; ++kt)
        bfr[kt] = *reinterpret_cast<const f16x8*>(wo + (nt * 16 + l15) * 128 + kt * 32 + g * 8);
      f32x4 acc = {0.f, 0.f, 0.f, 0.f};
#pragma unroll
      for (int kt = 0; kt < 4; ++kt)
        acc = __builtin_amdgcn_mfma_f32_16x16x32_f16(aO[kt], bfr[kt], acc, 0, 0, 0);
#pragma unroll
      for (int p = 0; p < 4; ++p) {
        int row = wid * 32 + mt * 16 + g * 4 + p;
        out[((size_t)r * SS + row) * CC + nt * 16 + l15] = (acc[p] + bcol) * qm[p];
      }
    }
  }
}

extern "C" void kernel_launch(void* const* d_in, const int* in_sizes, int n_in,
                              void* d_out, int out_size, void* d_ws, size_t ws_size,
                              hipStream_t stream) {
  const float* z   = (const float*)d_in[0];
  const unsigned char* pmask = (const unsigned char*)d_in[1];  // dtype sniffed on device
  const float* lnw = (const float*)d_in[2];
  const float* lnb = (const float*)d_in[3];
  const float* Wq  = (const float*)d_in[4];
  const float* bq  = (const float*)d_in[5];
  const float* Wk  = (const float*)d_in[6];
  const float* bk  = (const float*)d_in[7];
  const float* Wv  = (const float*)d_in[8];
  const float* bv  = (const float*)d_in[9];
  const float* Wb  = (const float*)d_in[10];
  const float* Wo  = (const float*)d_in[11];
  const float* bo  = (const float*)d_in[12];
  f16* ws = (f16*)d_ws;

  prep_weights<<<264, 256, 0, stream>>>(Wq, Wk, Wv, Wo, Wb, ws);
  tri_fused<<<512, 512, 0, stream>>>(z, pmask, lnw, lnb, bq, bk, bv, bo,
                                     ws, (float*)d_out);
}